// Round 5
// baseline (23.888 us; speedup 1.0000x reference)
//
#include <hip/hip_runtime.h>

namespace {
constexpr int GS = 128;
constexpr int NPTS = GS * GS;          // 16384 points per grid
constexpr float RES = 0.25f;
constexpr float RES2 = RES * RES;
constexpr int NGRIDS = 16;
constexpr int PW = 136;                // padded width  (4-col border each side, 16B-aligned rows)
constexpr int PH = 136;                // padded height
constexpr int PADN = PW * PH;          // elems per padded grid
constexpr float PADV = 1.0e18f;        // (za-PADV)^2 ~ 1e36: finite, never wins
constexpr int BLOCK = 256;
constexpr int QPT = 4;                 // queries per thread (one float4 column group)
constexpr int TASKS_PER_PAIR = NPTS / QPT;               // 4096
constexpr int BLOCKS_PER_PAIR = TASKS_PER_PAIR / BLOCK;  // 16
constexpr int NPAIRS = NGRIDS * 2;                       // 32
constexpr int NBLOCKS = NPAIRS * BLOCKS_PER_PAIR;        // 512
constexpr int PAD_QUADS = 2 * NGRIDS * PH * (PW / 4);    // 147968 float4s
}

// Build 32 padded grids (pred -> 0..15, gt -> 16..31) in workspace.
// Column border is exactly one float4 wide, so no quad straddles the edge.
__global__ __launch_bounds__(BLOCK) void pad_kernel(
    const float* __restrict__ pred, const float* __restrict__ gt,
    float* __restrict__ wpad)
{
    const int e4 = blockIdx.x * BLOCK + threadIdx.x;
    constexpr int QPG = PH * (PW / 4);     // 4624 quads per grid
    const int p   = e4 / QPG;
    const int rem = e4 - p * QPG;
    const int pr  = rem / (PW / 4);
    const int c4  = rem - pr * (PW / 4);
    const int r  = pr - 4;                 // source row
    const int c0 = 4 * c4 - 4;             // source col of quad start
    float4 v = make_float4(PADV, PADV, PADV, PADV);
    if (r >= 0 && r < GS && c0 >= 0 && c0 + 3 < GS) {
        const float* src = (p < NGRIDS) ? pred + p * NPTS : gt + (p - NGRIDS) * NPTS;
        v = *reinterpret_cast<const float4*>(src + r * GS + c0);
    }
    reinterpret_cast<float4*>(wpad)[e4] = v;
}

// One thread = 4 consecutive-column queries. Phase A: 7-row x 12-col padded
// window via 21 float4 loads, register-reused across the 4 queries; planar
// terms are compile-time constants (no clamping thanks to padding). Exact-done
// if best <= (4*RES)^2 = 1.0 (in-grid cells at Chebyshev radius >= 4 have
// planar >= 1.0). Phase B: wave-cooperative scan of rare stragglers over the
// ORIGINAL grid with clamped indexing; one pass with K = ceil(4*sqrt(bestA))
// is exact (cells at radius >= K have planar >= (K*RES)^2 >= bestA).
__global__ __launch_bounds__(BLOCK) void chamfer_kernel(
    const float* __restrict__ pred, const float* __restrict__ gt,
    const float* __restrict__ wpad, float* __restrict__ partial)
{
    const int bid = blockIdx.x;
    const int pair = bid >> 4;             // BLOCKS_PER_PAIR = 16
    const int blkin = bid & (BLOCKS_PER_PAIR - 1);
    const int g = pair >> 1;
    const int dir = pair & 1;
    const float* __restrict__ A   = (dir == 0) ? gt + g * NPTS : pred + g * NPTS;
    const float* __restrict__ DBo = (dir == 0) ? pred + g * NPTS : gt + g * NPTS;
    const float* __restrict__ DBp = wpad + ((dir == 0) ? g : NGRIDS + g) * PADN;

    const int tid = threadIdx.x;
    const int task = blkin * BLOCK + tid;  // 0..4095 within pair
    const int ri  = task >> 5;             // 32 column-groups per row
    const int ci0 = (task & 31) * 4;

    float za[QPT];
    {
        const float4 aq = *reinterpret_cast<const float4*>(A + ri * GS + ci0);
        za[0] = aq.x; za[1] = aq.y; za[2] = aq.z; za[3] = aq.w;
    }

    float acc[QPT][2];
    #pragma unroll
    for (int j = 0; j < QPT; ++j) { acc[j][0] = 1e30f; acc[j][1] = 1e30f; }

    // phase A: rows ri-3..ri+3 -> padded rows ri+1..ri+7; cols ci0-4..ci0+7
    #pragma unroll
    for (int dr = -3; dr <= 3; ++dr) {
        const float* rp = DBp + (ri + dr + 4) * PW + ci0;  // pc base = ci0 (16B-aligned)
        const float4 q0 = *reinterpret_cast<const float4*>(rp);
        const float4 q1 = *reinterpret_cast<const float4*>(rp + 4);
        const float4 q2 = *reinterpret_cast<const float4*>(rp + 8);
        const float z[12] = {q0.x, q0.y, q0.z, q0.w,
                             q1.x, q1.y, q1.z, q1.w,
                             q2.x, q2.y, q2.z, q2.w};
        #pragma unroll
        for (int j = 0; j < QPT; ++j) {
            #pragma unroll
            for (int dc = -3; dc <= 3; ++dc) {
                const float dz = za[j] - z[j + dc + 4];   // static index
                const float c2 = (float)(dr * dr + dc * dc) * RES2;
                acc[j][dc & 1] = fminf(acc[j][dc & 1], fmaf(dz, dz, c2));
            }
        }
    }
    float best[QPT];
    #pragma unroll
    for (int j = 0; j < QPT; ++j) best[j] = fminf(acc[j][0], acc[j][1]);

    // phase B: wave-cooperative straggler finish, per query slot
    const int lane = tid & 63;
    const int lr = lane >> 3, lc = lane & 7;  // 8x8 lane tile
    #pragma unroll
    for (int j = 0; j < QPT; ++j) {
        unsigned long long pend = __ballot(best[j] > 1.0f);
        while (pend) {
            const int src = __ffsll(pend) - 1;
            pend &= pend - 1;
            const int qri = __shfl(ri, src);
            const int qci = __shfl(ci0, src) + j;
            const float qza = __shfl(za[j], src);
            const float qb  = __shfl(best[j], src);
            int K = (int)(4.0f * sqrtf(qb)) + 1;  // >= ceil(4*sqrt(qb))
            K = min(K, GS - 1);
            float m = 1e30f;
            for (int tr = -K; tr <= K; tr += 8) {
                const int dr = tr + lr;
                if (dr > K) continue;
                const int r = min(max(qri + dr, 0), GS - 1);
                const float dx = (float)(qri - r) * RES;
                const float dxx2 = dx * dx;
                const float* __restrict__ row = DBo + r * GS;
                for (int tc = -K; tc <= K; tc += 8) {
                    const int dc = tc + lc;
                    if (dc > K) continue;
                    const int c = min(max(qci + dc, 0), GS - 1);
                    const float dy = (float)(qci - c) * RES;
                    const float dz = qza - row[c];
                    m = fminf(m, fmaf(dz, dz, fmaf(dy, dy, dxx2)));
                }
            }
            #pragma unroll
            for (int off = 32; off > 0; off >>= 1) m = fminf(m, __shfl_xor(m, off));
            if (lane == src) best[j] = fminf(best[j], m);
        }
    }

    // block sum-reduction -> one partial per block
    float s = (best[0] + best[1]) + (best[2] + best[3]);
    for (int off = 32; off > 0; off >>= 1) s += __shfl_down(s, off);
    __shared__ float wsum[BLOCK / 64];
    if ((tid & 63) == 0) wsum[tid >> 6] = s;
    __syncthreads();
    if (tid == 0) {
        float t = 0.0f;
        #pragma unroll
        for (int w = 0; w < BLOCK / 64; ++w) t += wsum[w];
        partial[bid] = t;
    }
}

__global__ __launch_bounds__(512) void reduce_kernel(
    const float* __restrict__ partial, float* __restrict__ out)
{
    const int tid = threadIdx.x;
    float s = partial[tid];                // NBLOCKS = 512
    for (int off = 32; off > 0; off >>= 1) s += __shfl_down(s, off);
    __shared__ float wsum[8];
    if ((tid & 63) == 0) wsum[tid >> 6] = s;
    __syncthreads();
    if (tid == 0) {
        float t = 0.0f;
        #pragma unroll
        for (int w = 0; w < 8; ++w) t += wsum[w];
        *out = t * (1.0f / NGRIDS);
    }
}

extern "C" void kernel_launch(void* const* d_in, const int* in_sizes, int n_in,
                              void* d_out, int out_size, void* d_ws, size_t ws_size,
                              hipStream_t stream) {
    const float* pred = (const float*)d_in[0];  // inputs (1,1,512,512)
    const float* gt   = (const float*)d_in[1];  // targets (1,512,512)
    float* wpad    = (float*)d_ws;              // 32 * PADN floats
    float* partial = wpad + 2 * NGRIDS * PADN;  // + NBLOCKS floats
    float* out = (float*)d_out;
    pad_kernel<<<PAD_QUADS / BLOCK, BLOCK, 0, stream>>>(pred, gt, wpad);
    chamfer_kernel<<<NBLOCKS, BLOCK, 0, stream>>>(pred, gt, wpad, partial);
    reduce_kernel<<<1, 512, 0, stream>>>(partial, out);
}

// Round 6
// 17.095 us; speedup vs baseline: 1.3974x; 1.3974x over previous
//
#include <hip/hip_runtime.h>

namespace {
constexpr int GS = 128;
constexpr int NPTS = GS * GS;          // 16384 points per grid
constexpr float RES = 0.25f;
constexpr int NGRIDS = 16;
constexpr int BLOCK = 256;
constexpr int CHUNKS = NPTS / BLOCK;   // 64 chunks per (grid,dir)
constexpr int NBLOCKS = NGRIDS * 2 * CHUNKS;  // 2048
}

// One thread per query point, 2048 blocks (32 waves/CU: TLP hides load latency).
// Phase A: 7x7 SUPERSET window anchored at clamped base (rb,cb) — always
// in-grid, covers the true clamped radius-3 neighborhood, single address calc,
// all 49 loads use immediate offsets. Exact-done iff best <= (4*RES)^2 = 1.0.
// Phase B: wave-cooperative scan of rare stragglers (broadcast one at a time,
// 64 lanes tile the (2K+1)^2 square, K = ceil(4*sqrt(bestA)) — one pass exact).
__global__ __launch_bounds__(BLOCK, 8) void chamfer_kernel(
    const float* __restrict__ pred, const float* __restrict__ gt,
    float* __restrict__ partial)
{
    const int bid = blockIdx.x;
    const int chunk = bid & (CHUNKS - 1);
    const int pair = bid >> 6;
    const int g = pair >> 1;
    const int dir = pair & 1;
    const float* __restrict__ A  = (dir == 0) ? gt + g * NPTS : pred + g * NPTS;
    const float* __restrict__ DB = (dir == 0) ? pred + g * NPTS : gt + g * NPTS;

    const int tid = threadIdx.x;
    const int i = chunk * BLOCK + tid;
    const int ri = i >> 7;
    const int ci = i & (GS - 1);
    const float za = A[i];

    // superset window base: clamp the BASE, not each cell
    const int rb = min(max(ri, 3), GS - 4);
    const int cb = min(max(ci, 3), GS - 4);
    const float* __restrict__ wbase = DB + (rb - 3) * GS + (cb - 3);

    // per-axis planar terms (runtime, but only 7+7 of them)
    float dx2[7], dy2[7];
    #pragma unroll
    for (int t = 0; t < 7; ++t) {
        const float dx = (float)(ri - (rb - 3 + t)) * RES;
        dx2[t] = dx * dx;
        const float dy = (float)(ci - (cb - 3 + t)) * RES;
        dy2[t] = dy * dy;
    }

    // phase A: 49 loads, all immediate offsets off one base; 4 min accumulators
    float bacc[4] = {1e30f, 1e30f, 1e30f, 1e30f};
    #pragma unroll
    for (int a = 0; a < 7; ++a) {
        #pragma unroll
        for (int b = 0; b < 7; ++b) {
            const float z = wbase[a * GS + b];          // imm offset a*512+b*4
            const float dz = za - z;
            const int t = a * 7 + b;
            bacc[t & 3] = fminf(bacc[t & 3], fmaf(dz, dz, dx2[a] + dy2[b]));
        }
    }
    float best = fminf(fminf(bacc[0], bacc[1]), fminf(bacc[2], bacc[3]));

    // phase B: wave-cooperative straggler finish (rare)
    const int lane = tid & 63;
    const int lr = lane >> 3, lc = lane & 7;   // 8x8 lane tile
    unsigned long long pend = __ballot(best > 1.0f);
    while (pend) {
        const int src = __ffsll(pend) - 1;
        pend &= pend - 1;
        const int qri = __shfl(ri, src);
        const int qci = __shfl(ci, src);
        const float qza = __shfl(za, src);
        const float qb  = __shfl(best, src);
        int K = (int)(4.0f * sqrtf(qb)) + 1;   // >= ceil(4*sqrt(qb))
        K = min(K, GS - 1);
        float m = 1e30f;
        for (int tr = -K; tr <= K; tr += 8) {
            const int dr = tr + lr;
            if (dr > K) continue;
            const int r = min(max(qri + dr, 0), GS - 1);
            const float dx = (float)(qri - r) * RES;
            const float dxx2 = dx * dx;
            const float* __restrict__ row = DB + r * GS;
            for (int tc = -K; tc <= K; tc += 8) {
                const int dc = tc + lc;
                if (dc > K) continue;
                const int c = min(max(qci + dc, 0), GS - 1);
                const float dy = (float)(qci - c) * RES;
                const float dz = qza - row[c];
                m = fminf(m, fmaf(dz, dz, fmaf(dy, dy, dxx2)));
            }
        }
        #pragma unroll
        for (int off = 32; off > 0; off >>= 1) m = fminf(m, __shfl_xor(m, off));
        if (lane == src) best = fminf(best, m);
    }

    // block sum-reduction -> one partial per block (no atomics)
    for (int off = 32; off > 0; off >>= 1) best += __shfl_down(best, off);
    __shared__ float wsum[BLOCK / 64];
    if ((tid & 63) == 0) wsum[tid >> 6] = best;
    __syncthreads();
    if (tid == 0) {
        float s = 0.0f;
        #pragma unroll
        for (int w = 0; w < BLOCK / 64; ++w) s += wsum[w];
        partial[bid] = s;
    }
}

__global__ __launch_bounds__(1024) void reduce_kernel(
    const float* __restrict__ partial, float* __restrict__ out)
{
    const int tid = threadIdx.x;
    float s = partial[tid] + partial[tid + 1024];   // NBLOCKS = 2048
    for (int off = 32; off > 0; off >>= 1) s += __shfl_down(s, off);
    __shared__ float wsum[16];
    if ((tid & 63) == 0) wsum[tid >> 6] = s;
    __syncthreads();
    if (tid == 0) {
        float t = 0.0f;
        #pragma unroll
        for (int w = 0; w < 16; ++w) t += wsum[w];
        *out = t * (1.0f / NGRIDS);
    }
}

extern "C" void kernel_launch(void* const* d_in, const int* in_sizes, int n_in,
                              void* d_out, int out_size, void* d_ws, size_t ws_size,
                              hipStream_t stream) {
    const float* pred = (const float*)d_in[0];  // inputs (1,1,512,512)
    const float* gt   = (const float*)d_in[1];  // targets (1,512,512)
    float* partial = (float*)d_ws;              // 2048 floats
    float* out = (float*)d_out;
    chamfer_kernel<<<NBLOCKS, BLOCK, 0, stream>>>(pred, gt, partial);
    reduce_kernel<<<1, 1024, 0, stream>>>(partial, out);
}